// Round 1
// 677.710 us; speedup vs baseline: 1.2033x; 1.2033x over previous
//
#include <hip/hip_runtime.h>
#include <cstdint>
#include <cstddef>

// ---------------------------------------------------------------------------
// PiFormerFFN R5: 256x256-tile 8-phase GEMM (HK-style schedule, plain HIP).
//   out = gelu_q(x @ W1^T) @ W2^T
//
// Structure (per guide's verified m201 template):
//   - 512 threads = 8 waves (2 M-waves x 4 N-waves), tile 256x256, BK=64
//   - LDS 128 KiB: 2 buffers x {B-half0, B-half1, A-half0, A-half1} x 16 KiB
//   - mfma_f32_16x16x32_bf16; per wave 128x64 output = 8x4 frags
//   - per K-tile 4 phases, each: {ds_read subtile | stage 1 half-tile |
//       barrier | setprio(1) 16xMFMA setprio(0) | barrier}
//   - staging is a continuous half-tile sequence 7 phases ahead of use;
//     counted s_waitcnt vmcnt(6) ONCE per K-tile (never 0 in main loop)
//   - st_16x32 swizzle (byte ^= ((byte>>9)&1)<<5 within 1 KiB subtile),
//     pre-applied in the packed GLOBAL layout so global_load_lds stays linear
//     and ds_read_b128 applies the same involution (rule #21).
//
// Packed operand layout for [R,K] (bf16): panel p=row/256, ktile t=k/64,
//   half h=(row%256)/128 -> 16 KiB block; inside: subtile s=(rowh/16)*2+(k%64)/32
//   (1 KiB, row-major 16x32), then swizzled: phys = logical ^ ((logical>>9&1)<<5).
//
// Race-freedom of the schedule (derived, see phase comments):
//   reads of a region finish >=1 barrier before the stage that overwrites it;
//   vmcnt(6) at tile end == 3 newest half-tiles in flight, tile t+1 landed.
// ---------------------------------------------------------------------------

typedef __bf16 bf16_t;
typedef bf16_t bf16x8 __attribute__((ext_vector_type(8)));
typedef float  floatx4 __attribute__((ext_vector_type(4)));

#define AS1 __attribute__((address_space(1)))
#define AS3 __attribute__((address_space(3)))

__device__ __forceinline__ void async_cp16(const void* g, void* l) {
    __builtin_amdgcn_global_load_lds((const AS1 void*)g, (AS3 void*)l, 16, 0, 0);
}

// tanh-approx gelu: gelu = x * (1 - 1/(1+e^{2u})), u = k0*(x + k1*x^3)
__device__ __forceinline__ float gelu_fast(float x) {
    const float C0 = 1.5957691216057308f;   // 2*sqrt(2/pi)
    const float C1 = 0.0713548163f;         // C0 * 0.044715
    float u2 = x * fmaf(C1, x * x, C0);
    float e  = __expf(u2);
    float r  = __builtin_amdgcn_rcpf(1.0f + e);
    return x * (1.0f - r);
}

// fp32 [R,K] row-major -> packed+swizzled bf16. One thread per 16B chunk.
// tshift = log2(K/64). Writes perfectly coalesced; reads are 128B-segment
// gathers (4 threads x 32B per source row).
__global__ __launch_bounds__(256)
void cvt_pack_swz(const float* __restrict__ src, bf16_t* __restrict__ dst,
                  int K, int tshift)
{
    const size_t   oc = (size_t)blockIdx.x * 256 + threadIdx.x;  // 16B chunk
    const uint32_t ho = ((uint32_t)oc & 1023u) * 16u;  // phys byte in half-tile
    const size_t   region = oc >> 10;                  // 16 KiB half-tile index
    const int      h  = (int)(region & 1);
    const size_t   pt = region >> 1;
    const int      t  = (int)(pt & ((1u << tshift) - 1));
    const size_t   p  = pt >> tshift;
    // physical -> logical (involution)
    const uint32_t L = ho ^ (((ho >> 9) & 1u) << 5);
    const int      s = (int)(L >> 10);                 // subtile 0..15
    const uint32_t u = L & 1023u;
    const size_t   row = p * 256 + (size_t)(h * 128 + (s >> 1) * 16 + (int)(u >> 6));
    const int      k   = (t << 6) + (s & 1) * 32 + (int)((u & 63u) >> 1);
    const float* sp = src + row * (size_t)K + k;
    float4 a = *(const float4*)sp;
    float4 b = *(const float4*)(sp + 4);
    bf16x8 o;
    o[0] = (bf16_t)a.x; o[1] = (bf16_t)a.y; o[2] = (bf16_t)a.z; o[3] = (bf16_t)a.w;
    o[4] = (bf16_t)b.x; o[5] = (bf16_t)b.y; o[6] = (bf16_t)b.z; o[7] = (bf16_t)b.w;
    *(bf16x8*)(dst + oc * 8) = o;
}

// C = A * B^T, A/B in packed+swizzled layout.
// ACT=true: C is the packed act buffer (bf16), fused quant+gelu via LDS repack.
// ACT=false: C row-major fp32 [M,N].
template<bool ACT, typename OutT>
__global__ __launch_bounds__(512, 2)
void gemm256(const bf16_t* __restrict__ A, const bf16_t* __restrict__ B,
             OutT* __restrict__ C, int M, int N, int K, int nbxs)
{
    __shared__ __align__(16) bf16_t lds[65536];        // 128 KiB
    char* const ldsb = (char*)lds;

    const int NT  = K >> 6;                            // K-tiles
    const int id  = blockIdx.x;
    const int nwg = gridDim.x;
    // bijective XCD swizzle (nwg % 8 == 0 for both GEMMs)
    const int sw = (id & 7) * (nwg >> 3) + (id >> 3);
    const int by = sw >> nbxs;
    const int bx = sw & ((1 << nbxs) - 1);

    const int tid  = threadIdx.x;
    const int lane = tid & 63;
    const int wave = tid >> 6;
    const int wm = wave >> 2;                          // 0..1: M-half
    const int wn = wave & 3;                           // 0..3: N-quarter

    const bf16_t* const Ap = A + (size_t)by * NT * 16384;   // 256-row panel
    const bf16_t* const Bp = B + (size_t)bx * NT * 16384;

    // per-lane swizzled frag offset: logical (lane&15)*64 + (lane>>4)*16
    uint32_t lsw = (uint32_t)(((lane & 15) << 6) + ((lane >> 4) << 4));
    lsw ^= ((lsw >> 9) & 1u) << 5;

    // LDS region bases (bytes): {0:B0, 1:B1, 2:A0, 3:A1} per buffer
    const uint32_t aBase = (uint32_t)(2 + wm) << 14;   // wave's own A half
    const uint32_t bBase = (uint32_t)(wn >> 1) << 14;  // wave's own B half
    const int bSub = (wn & 1) * 4;                     // col-subtile offset

    floatx4 acc[8][4];
    #pragma unroll
    for (int i = 0; i < 8; ++i)
      #pragma unroll
      for (int j = 0; j < 4; ++j)
        acc[i][j] = (floatx4)0.0f;

    // stage half j of K-tile t: 2 x global_load_lds(16B)/thread, linear dest.
    auto stage = [&](int t, int j) {
        const bf16_t* g = (j < 2) ? (Bp + (size_t)t * 16384 + (size_t)j * 8192)
                                  : (Ap + (size_t)t * 16384 + (size_t)(j - 2) * 8192);
        char* l = ldsb + (((t & 1) << 16) + (j << 14));
        async_cp16((const char*)g + tid * 16, l + tid * 16);
        async_cp16((const char*)g + 8192 + tid * 16, l + 8192 + tid * 16);
    };

    // prologue: half-tile sequence h=0..6 (tile0 {B0,B1,A0,A1} + tile1 {B0,B1,A0})
    stage(0, 0); stage(0, 1); stage(0, 2); stage(0, 3);
    stage(1, 0); stage(1, 1); stage(1, 2);
    asm volatile("s_waitcnt vmcnt(6)" ::: "memory");   // tile0 landed
    __builtin_amdgcn_s_barrier();

    for (int t = 0; t < NT; ++t) {
        const char* aB = ldsb + ((t & 1) << 16) + aBase;
        const char* bB = ldsb + ((t & 1) << 16) + bBase;
        const bool s1 = (t + 1 < NT);
        const bool s2 = (t + 2 < NT);

        bf16x8 af[4][2], bfr[4][2];

        // -------- phase 0: read A rows0-3 + ALL B; stage (t+1).A1 -> other buf;
        //                   MFMA quadrant (rows0-3 x cols0-1)
        #pragma unroll
        for (int fm = 0; fm < 4; ++fm)
          #pragma unroll
          for (int ks = 0; ks < 2; ++ks)
            af[fm][ks] = *(const bf16x8*)(aB + ((((fm << 1) + ks) << 10) | lsw));
        #pragma unroll
        for (int fn = 0; fn < 4; ++fn)
          #pragma unroll
          for (int ks = 0; ks < 2; ++ks)
            bfr[fn][ks] = *(const bf16x8*)(bB + (((((bSub + fn) << 1) + ks) << 10) | lsw));
        if (s1) stage(t + 1, 3);
        __builtin_amdgcn_s_barrier();
        __builtin_amdgcn_s_setprio(1);
        #pragma unroll
        for (int ks = 0; ks < 2; ++ks)
          #pragma unroll
          for (int fm = 0; fm < 4; ++fm)
            #pragma unroll
            for (int fn = 0; fn < 2; ++fn)
              acc[fm][fn] = __builtin_amdgcn_mfma_f32_16x16x32_bf16(
                  af[fm][ks], bfr[fn][ks], acc[fm][fn], 0, 0, 0);
        __builtin_amdgcn_s_setprio(0);
        // guard: ALL phase-0 ds_reads serviced before B0 is restaged next phase
        asm volatile("s_waitcnt lgkmcnt(0)" ::: "memory");
        __builtin_amdgcn_s_barrier();

        // -------- phase 1: stage (t+2).B0 (this buf; B reads done in ph0);
        //                   MFMA quadrant (rows0-3 x cols2-3)
        if (s2) stage(t + 2, 0);
        __builtin_amdgcn_s_barrier();
        __builtin_amdgcn_s_setprio(1);
        #pragma unroll
        for (int ks = 0; ks < 2; ++ks)
          #pragma unroll
          for (int fm = 0; fm < 4; ++fm)
            #pragma unroll
            for (int fn = 2; fn < 4; ++fn)
              acc[fm][fn] = __builtin_amdgcn_mfma_f32_16x16x32_bf16(
                  af[fm][ks], bfr[fn][ks], acc[fm][fn], 0, 0, 0);
        __builtin_amdgcn_s_setprio(0);
        __builtin_amdgcn_s_barrier();

        // -------- phase 2: read A rows4-7; stage (t+2).B1;
        //                   MFMA quadrant (rows4-7 x cols0-1)
        #pragma unroll
        for (int fm = 0; fm < 4; ++fm)
          #pragma unroll
          for (int ks = 0; ks < 2; ++ks)
            af[fm][ks] = *(const bf16x8*)(aB + (((((4 + fm) << 1) + ks) << 10) | lsw));
        if (s2) stage(t + 2, 1);
        __builtin_amdgcn_s_barrier();
        __builtin_amdgcn_s_setprio(1);
        #pragma unroll
        for (int ks = 0; ks < 2; ++ks)
          #pragma unroll
          for (int fm = 0; fm < 4; ++fm)
            #pragma unroll
            for (int fn = 0; fn < 2; ++fn)
              acc[4 + fm][fn] = __builtin_amdgcn_mfma_f32_16x16x32_bf16(
                  af[fm][ks], bfr[fn][ks], acc[4 + fm][fn], 0, 0, 0);
        __builtin_amdgcn_s_setprio(0);
        __builtin_amdgcn_s_barrier();

        // -------- phase 3: stage (t+2).A0 (A reads done in ph2);
        //                   MFMA quadrant (rows4-7 x cols2-3); tile-end vmcnt
        if (s2) stage(t + 2, 2);
        __builtin_amdgcn_s_barrier();
        __builtin_amdgcn_s_setprio(1);
        #pragma unroll
        for (int ks = 0; ks < 2; ++ks)
          #pragma unroll
          for (int fm = 0; fm < 4; ++fm)
            #pragma unroll
            for (int fn = 2; fn < 4; ++fn)
              acc[4 + fm][fn] = __builtin_amdgcn_mfma_f32_16x16x32_bf16(
                  af[fm][ks], bfr[fn][ks], acc[4 + fm][fn], 0, 0, 0);
        __builtin_amdgcn_s_setprio(0);
        if (s2)      asm volatile("s_waitcnt vmcnt(6)" ::: "memory"); // tile t+1 landed
        else if (s1) asm volatile("s_waitcnt vmcnt(0)" ::: "memory"); // drain tail
        __builtin_amdgcn_s_barrier();
    }

    if constexpr (ACT) {
        // Fused quant+gelu; repack into act's packed+swizzled layout via LDS.
        // Wave's 128x64 output == exactly one half-tile region:
        //   panel=by, ktile=bx*4+wn, half=wm  ->  LDS region wn*2+wm.
        __syncthreads();
        const uint32_t rbase = (uint32_t)(wn * 2 + wm) << 14;
        #pragma unroll
        for (int fm = 0; fm < 8; ++fm)
          #pragma unroll
          for (int fn = 0; fn < 4; ++fn)
            #pragma unroll
            for (int r = 0; r < 4; ++r) {
                float h = acc[fm][fn][r];
                float q = rintf(h * 10.0f);             // round half-to-even
                q = fminf(fmaxf(q, -32768.0f), 32767.0f);
                h = gelu_fast(q * 0.1f);
                uint32_t L = ((uint32_t)((fm << 1) + (fn >> 1)) << 10)
                           + (uint32_t)((((lane >> 4) << 2) + r) << 6)
                           + (uint32_t)((((fn & 1) << 4) + (lane & 15)) << 1);
                uint32_t P = L ^ (((L >> 9) & 1u) << 5);
                *(bf16_t*)(ldsb + rbase + P) = (bf16_t)h;
            }
        __syncthreads();
        // copy out: 8 contiguous 16 KiB runs, 16B/thread/iter, fully coalesced
        const int nkt2 = N >> 6;
        bf16_t* const Cb = (bf16_t*)C;
        #pragma unroll
        for (int it = 0; it < 16; ++it) {
            const int ch = it * 512 + tid;              // chunk 0..8191
            const int rg = ch >> 10;                    // LDS region
            const int c  = ch & 1023;
            const size_t gr = ((size_t)by * nkt2 + (size_t)(bx * 4) + (rg >> 1)) * 2
                            + (size_t)(rg & 1);
            bf16x8 v = *(const bf16x8*)(ldsb + (size_t)ch * 16);
            *(bf16x8*)((char*)Cb + gr * 16384 + (size_t)c * 16) = v;
        }
    } else {
        // Row-major fp32 stores (quarter-wave writes 64B contiguous).
        const int r0 = by * 256 + wm * 128;
        const int c0 = bx * 256 + wn * 64;
        #pragma unroll
        for (int fm = 0; fm < 8; ++fm)
          #pragma unroll
          for (int fn = 0; fn < 4; ++fn) {
            const int col = c0 + fn * 16 + (lane & 15);
            #pragma unroll
            for (int r = 0; r < 4; ++r) {
              const int row = r0 + fm * 16 + ((lane >> 4) << 2) + r;
              C[(size_t)row * N + col] = (OutT)acc[fm][fn][r];
            }
          }
    }
}

extern "C" void kernel_launch(void* const* d_in, const int* in_sizes, int n_in,
                              void* d_out, int out_size, void* d_ws, size_t ws_size,
                              hipStream_t stream)
{
    const int M  = 8192;   // BATCH*SEQ
    const int DM = 2048;   // d_model
    const int DF = 8192;   // d_ff

    const float* x  = (const float*)d_in[0];
    const float* W1 = (const float*)d_in[1];
    const float* W2 = (const float*)d_in[2];
    float* out = (float*)d_out;

    bf16_t* xb  = (bf16_t*)d_ws;                      // packed [M,DM]
    bf16_t* w1b = xb  + (size_t)M  * DM;              // packed [DF,DM]
    bf16_t* w2b = w1b + (size_t)DF * DM;              // packed [DM,DF]
    bf16_t* act = w2b + (size_t)DM * DF;              // packed [M,DF]

    // converters: one thread per 16B output chunk; tshift = log2(K/64)
    cvt_pack_swz<<<8192, 256, 0, stream>>>(x,  xb,  DM, 5);
    cvt_pack_swz<<<8192, 256, 0, stream>>>(W1, w1b, DM, 5);
    cvt_pack_swz<<<8192, 256, 0, stream>>>(W2, w2b, DF, 7);

    // GEMM1 + fused quant/gelu: act = pack(gelu_q(xb @ w1b^T)); grid 32x32
    gemm256<true, bf16_t><<<dim3(1024), 512, 0, stream>>>(xb, w1b, act, M, DF, DM, 5);
    // GEMM2: out = act @ w2b^T; grid 32x8 = 256 (1 block/CU)
    gemm256<false, float><<<dim3(256), 512, 0, stream>>>(act, w2b, out, M, DM, DF, 3);
}

// Round 2
// 637.977 us; speedup vs baseline: 1.2782x; 1.0623x over previous
//
#include <hip/hip_runtime.h>
#include <cstdint>
#include <cstddef>

// ---------------------------------------------------------------------------
// PiFormerFFN R6: 256x256 tile, 8-wave, counted-vmcnt K-loop, plain HIP.
//   out = gelu_q(x @ W1^T) @ W2^T
//
// vs R5 (same layouts/converters/epilogues): K-loop restructured from the
// 8-barrier 4-phase form to a 2-barrier 4-cluster form with reads spread and
// pre-issued one cluster ahead:
//   S0: read af_lo(8)+b23(4)      | MFMA q0 (af_lo x b01, b01 pre-read prev S3)
//   S1: lgkmcnt(0); BARRIER       | stage (t+2).B | MFMA q1 (af_lo x b23)
//   S2: read af_hi(8)             | MFMA q2 (af_hi x b01)
//   S3: vmcnt(4); BARRIER         | read next b01(4) | stage (t+2).A | MFMA q3
// Race-freedom:
//   - B-restage at S1 is after every wave's lgkmcnt(0)+barrier => all tile-t
//     LDS reads serviced before the DMA write can land.
//   - A-restage at S3 is after B2; every wave reaching B2 has issued its S2
//     MFMA => af_hi reads serviced (operand waits) before any A write lands.
//   - vmcnt(4) at S3: issue order ... (t+1).A[4] (t+2).B[4] => waiting to 4
//     outstanding guarantees all of tile t+1 is in LDS; (t+1).A has 4 phases
//     of flight. Tail: t+2>=NT -> vmcnt(0) once, at t=NT-2 only.
// Packed layout (unchanged): panel p=row/256, ktile t=k/64, half h -> 16 KiB
//   region; 16x32 subtiles, st_16x32 swizzle pre-applied in global memory so
//   global_load_lds dest stays linear and ds_read applies the involution.
// ---------------------------------------------------------------------------

typedef __bf16 bf16_t;
typedef bf16_t bf16x8 __attribute__((ext_vector_type(8)));
typedef float  floatx4 __attribute__((ext_vector_type(4)));

#define AS1 __attribute__((address_space(1)))
#define AS3 __attribute__((address_space(3)))

__device__ __forceinline__ void async_cp16(const void* g, void* l) {
    __builtin_amdgcn_global_load_lds((const AS1 void*)g, (AS3 void*)l, 16, 0, 0);
}

// tanh-approx gelu: gelu = x * (1 - 1/(1+e^{2u})), u = k0*(x + k1*x^3)
__device__ __forceinline__ float gelu_fast(float x) {
    const float C0 = 1.5957691216057308f;   // 2*sqrt(2/pi)
    const float C1 = 0.0713548163f;         // C0 * 0.044715
    float u2 = x * fmaf(C1, x * x, C0);
    float e  = __expf(u2);
    float r  = __builtin_amdgcn_rcpf(1.0f + e);
    return x * (1.0f - r);
}

// fp32 [R,K] row-major -> packed+swizzled bf16. One thread per 16B chunk.
__global__ __launch_bounds__(256)
void cvt_pack_swz(const float* __restrict__ src, bf16_t* __restrict__ dst,
                  int K, int tshift)
{
    const size_t   oc = (size_t)blockIdx.x * 256 + threadIdx.x;  // 16B chunk
    const uint32_t ho = ((uint32_t)oc & 1023u) * 16u;  // phys byte in half-tile
    const size_t   region = oc >> 10;                  // 16 KiB half-tile index
    const int      h  = (int)(region & 1);
    const size_t   pt = region >> 1;
    const int      t  = (int)(pt & ((1u << tshift) - 1));
    const size_t   p  = pt >> tshift;
    // physical -> logical (involution)
    const uint32_t L = ho ^ (((ho >> 9) & 1u) << 5);
    const int      s = (int)(L >> 10);                 // subtile 0..15
    const uint32_t u = L & 1023u;
    const size_t   row = p * 256 + (size_t)(h * 128 + (s >> 1) * 16 + (int)(u >> 6));
    const int      k   = (t << 6) + (s & 1) * 32 + (int)((u & 63u) >> 1);
    const float* sp = src + row * (size_t)K + k;
    float4 a = *(const float4*)sp;
    float4 b = *(const float4*)(sp + 4);
    bf16x8 o;
    o[0] = (bf16_t)a.x; o[1] = (bf16_t)a.y; o[2] = (bf16_t)a.z; o[3] = (bf16_t)a.w;
    o[4] = (bf16_t)b.x; o[5] = (bf16_t)b.y; o[6] = (bf16_t)b.z; o[7] = (bf16_t)b.w;
    *(bf16x8*)(dst + oc * 8) = o;
}

// C = A * B^T, A/B in packed+swizzled layout.
template<bool ACT, typename OutT>
__global__ __launch_bounds__(512, 2)
void gemm256(const bf16_t* __restrict__ A, const bf16_t* __restrict__ B,
             OutT* __restrict__ C, int M, int N, int K, int nbxs)
{
    __shared__ __align__(16) bf16_t lds[65536];        // 128 KiB
    char* const ldsb = (char*)lds;

    const int NT  = K >> 6;                            // K-tiles
    const int id  = blockIdx.x;
    const int nwg = gridDim.x;
    // bijective XCD swizzle (nwg % 8 == 0 for both GEMMs)
    const int sw = (id & 7) * (nwg >> 3) + (id >> 3);
    const int by = sw >> nbxs;
    const int bx = sw & ((1 << nbxs) - 1);

    const int tid  = threadIdx.x;
    const int lane = tid & 63;
    const int wave = tid >> 6;
    const int wm = wave >> 2;                          // 0..1: M-half
    const int wn = wave & 3;                           // 0..3: N-quarter

    const bf16_t* const Ap = A + (size_t)by * NT * 16384;   // 256-row panel
    const bf16_t* const Bp = B + (size_t)bx * NT * 16384;

    // per-lane swizzled frag offset: logical (lane&15)*64 + (lane>>4)*16
    uint32_t lsw = (uint32_t)(((lane & 15) << 6) + ((lane >> 4) << 4));
    lsw ^= ((lsw >> 9) & 1u) << 5;

    // LDS region bases (bytes): {0:B0, 1:B1, 2:A0, 3:A1} per buffer
    const uint32_t aBase = (uint32_t)(2 + wm) << 14;   // wave's own A half
    const uint32_t bBase = (uint32_t)(wn >> 1) << 14;  // wave's own B half
    const int bSub = (wn & 1) * 4;                     // col-subtile offset

    floatx4 acc[8][4];
    #pragma unroll
    for (int i = 0; i < 8; ++i)
      #pragma unroll
      for (int j = 0; j < 4; ++j)
        acc[i][j] = (floatx4)0.0f;

    // stage half j of K-tile t: 2 x global_load_lds(16B)/thread, linear dest.
    auto stage = [&](int t, int j) {
        const bf16_t* g = (j < 2) ? (Bp + (size_t)t * 16384 + (size_t)j * 8192)
                                  : (Ap + (size_t)t * 16384 + (size_t)(j - 2) * 8192);
        char* l = ldsb + (((t & 1) << 16) + (j << 14));
        async_cp16((const char*)g + tid * 16, l + tid * 16);
        async_cp16((const char*)g + 8192 + tid * 16, l + 8192 + tid * 16);
    };

    // prologue: tiles 0 and 1 fully staged (16 loads); wait tile 0 (leave 8)
    stage(0, 0); stage(0, 1); stage(0, 2); stage(0, 3);
    stage(1, 0); stage(1, 1); stage(1, 2); stage(1, 3);
    asm volatile("s_waitcnt vmcnt(8)" ::: "memory");   // tile0 landed
    __builtin_amdgcn_s_barrier();

    // pre-read tile0's b01 (fn0-1, both ks)
    bf16x8 b01[2][2];
    {
        const char* bB0 = ldsb + bBase;
        #pragma unroll
        for (int fn = 0; fn < 2; ++fn)
          #pragma unroll
          for (int ks = 0; ks < 2; ++ks)
            b01[fn][ks] = *(const bf16x8*)(bB0 + (((((bSub + fn) << 1) + ks) << 10) | lsw));
    }

    for (int t = 0; t < NT; ++t) {
        const char* aB  = ldsb + ((t & 1) << 16) + aBase;
        const char* bBc = ldsb + ((t & 1) << 16) + bBase;
        const bool s1 = (t + 1 < NT);
        const bool s2 = (t + 2 < NT);

        // ---- S0: read af_lo (fm0-3) + b23; MFMA q0 = acc[fm0-3][fn0-1]
        bf16x8 af[4][2], b23[2][2];
        #pragma unroll
        for (int fm = 0; fm < 4; ++fm)
          #pragma unroll
          for (int ks = 0; ks < 2; ++ks)
            af[fm][ks] = *(const bf16x8*)(aB + ((((fm << 1) + ks) << 10) | lsw));
        #pragma unroll
        for (int fn = 0; fn < 2; ++fn)
          #pragma unroll
          for (int ks = 0; ks < 2; ++ks)
            b23[fn][ks] = *(const bf16x8*)(bBc + (((((bSub + 2 + fn) << 1) + ks) << 10) | lsw));
        __builtin_amdgcn_s_setprio(1);
        #pragma unroll
        for (int ks = 0; ks < 2; ++ks)
          #pragma unroll
          for (int fm = 0; fm < 4; ++fm)
            #pragma unroll
            for (int fn = 0; fn < 2; ++fn)
              acc[fm][fn] = __builtin_amdgcn_mfma_f32_16x16x32_bf16(
                  af[fm][ks], b01[fn][ks], acc[fm][fn], 0, 0, 0);
        __builtin_amdgcn_s_setprio(0);

        // ---- S1: drain all tile-t reads; barrier; stage (t+2).B; MFMA q1
        asm volatile("s_waitcnt lgkmcnt(0)" ::: "memory");
        __builtin_amdgcn_s_barrier();
        if (s2) { stage(t + 2, 0); stage(t + 2, 1); }
        __builtin_amdgcn_s_setprio(1);
        #pragma unroll
        for (int ks = 0; ks < 2; ++ks)
          #pragma unroll
          for (int fm = 0; fm < 4; ++fm)
            #pragma unroll
            for (int fn = 0; fn < 2; ++fn)
              acc[fm][2 + fn] = __builtin_amdgcn_mfma_f32_16x16x32_bf16(
                  af[fm][ks], b23[fn][ks], acc[fm][2 + fn], 0, 0, 0);
        __builtin_amdgcn_s_setprio(0);

        // ---- S2: read af_hi (fm4-7); MFMA q2 = acc[fm4-7][fn0-1]
        bf16x8 ah[4][2];
        #pragma unroll
        for (int fm = 0; fm < 4; ++fm)
          #pragma unroll
          for (int ks = 0; ks < 2; ++ks)
            ah[fm][ks] = *(const bf16x8*)(aB + (((((4 + fm) << 1) + ks) << 10) | lsw));
        __builtin_amdgcn_s_setprio(1);
        #pragma unroll
        for (int ks = 0; ks < 2; ++ks)
          #pragma unroll
          for (int fm = 0; fm < 4; ++fm)
            #pragma unroll
            for (int fn = 0; fn < 2; ++fn)
              acc[4 + fm][fn] = __builtin_amdgcn_mfma_f32_16x16x32_bf16(
                  ah[fm][ks], b01[fn][ks], acc[4 + fm][fn], 0, 0, 0);
        __builtin_amdgcn_s_setprio(0);

        // ---- S3: tile t+1 landed gate; barrier; pre-read next b01;
        //          stage (t+2).A; MFMA q3 = acc[fm4-7][fn2-3]
        if (s2)      asm volatile("s_waitcnt vmcnt(4)" ::: "memory");
        else if (s1) asm volatile("s_waitcnt vmcnt(0)" ::: "memory");
        __builtin_amdgcn_s_barrier();
        if (s1) {
            const char* bBn = ldsb + (((t + 1) & 1) << 16) + bBase;
            #pragma unroll
            for (int fn = 0; fn < 2; ++fn)
              #pragma unroll
              for (int ks = 0; ks < 2; ++ks)
                b01[fn][ks] = *(const bf16x8*)(bBn + (((((bSub + fn) << 1) + ks) << 10) | lsw));
        }
        if (s2) { stage(t + 2, 2); stage(t + 2, 3); }
        __builtin_amdgcn_s_setprio(1);
        #pragma unroll
        for (int ks = 0; ks < 2; ++ks)
          #pragma unroll
          for (int fm = 0; fm < 4; ++fm)
            #pragma unroll
            for (int fn = 0; fn < 2; ++fn)
              acc[4 + fm][2 + fn] = __builtin_amdgcn_mfma_f32_16x16x32_bf16(
                  ah[fm][ks], b23[fn][ks], acc[4 + fm][2 + fn], 0, 0, 0);
        __builtin_amdgcn_s_setprio(0);
    }

    if constexpr (ACT) {
        // Fused quant+gelu; repack into act's packed+swizzled layout via LDS.
        __syncthreads();
        const uint32_t rbase = (uint32_t)(wn * 2 + wm) << 14;
        #pragma unroll
        for (int fm = 0; fm < 8; ++fm)
          #pragma unroll
          for (int fn = 0; fn < 4; ++fn)
            #pragma unroll
            for (int r = 0; r < 4; ++r) {
                float h = acc[fm][fn][r];
                float q = rintf(h * 10.0f);             // round half-to-even
                q = fminf(fmaxf(q, -32768.0f), 32767.0f);
                h = gelu_fast(q * 0.1f);
                uint32_t L = ((uint32_t)((fm << 1) + (fn >> 1)) << 10)
                           + (uint32_t)((((lane >> 4) << 2) + r) << 6)
                           + (uint32_t)((((fn & 1) << 4) + (lane & 15)) << 1);
                uint32_t P = L ^ (((L >> 9) & 1u) << 5);
                *(bf16_t*)(ldsb + rbase + P) = (bf16_t)h;
            }
        __syncthreads();
        // copy out: 8 contiguous 16 KiB runs, 16B/thread/iter, fully coalesced
        const int nkt2 = N >> 6;
        bf16_t* const Cb = (bf16_t*)C;
        #pragma unroll
        for (int it = 0; it < 16; ++it) {
            const int ch = it * 512 + tid;              // chunk 0..8191
            const int rg = ch >> 10;                    // LDS region
            const int c  = ch & 1023;
            const size_t gr = ((size_t)by * nkt2 + (size_t)(bx * 4) + (rg >> 1)) * 2
                            + (size_t)(rg & 1);
            bf16x8 v = *(const bf16x8*)(ldsb + (size_t)ch * 16);
            *(bf16x8*)((char*)Cb + gr * 16384 + (size_t)c * 16) = v;
        }
    } else {
        // Row-major fp32 stores (quarter-wave writes 64B contiguous).
        const int r0 = by * 256 + wm * 128;
        const int c0 = bx * 256 + wn * 64;
        #pragma unroll
        for (int fm = 0; fm < 8; ++fm)
          #pragma unroll
          for (int fn = 0; fn < 4; ++fn) {
            const int col = c0 + fn * 16 + (lane & 15);
            #pragma unroll
            for (int r = 0; r < 4; ++r) {
              const int row = r0 + fm * 16 + ((lane >> 4) << 2) + r;
              C[(size_t)row * N + col] = (OutT)acc[fm][fn][r];
            }
          }
    }
}

extern "C" void kernel_launch(void* const* d_in, const int* in_sizes, int n_in,
                              void* d_out, int out_size, void* d_ws, size_t ws_size,
                              hipStream_t stream)
{
    const int M  = 8192;   // BATCH*SEQ
    const int DM = 2048;   // d_model
    const int DF = 8192;   // d_ff

    const float* x  = (const float*)d_in[0];
    const float* W1 = (const float*)d_in[1];
    const float* W2 = (const float*)d_in[2];
    float* out = (float*)d_out;

    bf16_t* xb  = (bf16_t*)d_ws;                      // packed [M,DM]
    bf16_t* w1b = xb  + (size_t)M  * DM;              // packed [DF,DM]
    bf16_t* w2b = w1b + (size_t)DF * DM;              // packed [DM,DF]
    bf16_t* act = w2b + (size_t)DM * DF;              // packed [M,DF]

    // converters: one thread per 16B output chunk; tshift = log2(K/64)
    cvt_pack_swz<<<8192, 256, 0, stream>>>(x,  xb,  DM, 5);
    cvt_pack_swz<<<8192, 256, 0, stream>>>(W1, w1b, DM, 5);
    cvt_pack_swz<<<8192, 256, 0, stream>>>(W2, w2b, DF, 7);

    // GEMM1 + fused quant/gelu: act = pack(gelu_q(xb @ w1b^T)); grid 32x32
    gemm256<true, bf16_t><<<dim3(1024), 512, 0, stream>>>(xb, w1b, act, M, DF, DM, 5);
    // GEMM2: out = act @ w2b^T; grid 32x8 = 256 (1 block/CU)
    gemm256<false, float><<<dim3(256), 512, 0, stream>>>(act, w2b, out, M, DM, DF, 3);
}